// Round 17
// baseline (533.181 us; speedup 1.0000x reference)
//
#include <hip/hip_runtime.h>
#include <float.h>
#include <math.h>

// Problem constants (fixed by the reference: N=8192, D=512, k+1=31).
#define NN 8192
#define DD 512
#define TOPK 31
#define CAPW 192          // per-row candidate cap (typical cnt ~43)
#define DELTA 1.25e-3f    // sound |fp16-1-term approx - exact| bound:
                          // 2*2^-11*||e||^2 (9.8e-4) + f32 accum (~6e-5)

// Strategy (R24 = R23 with the pointer-arithmetic compile fix):
//   Bit-exact value chain (absmax 0.0 since R3):
//     h = relu(f*W1)*W2 ; n = sqrtf(numpy-pairwise sum h*h) ; e = h/n
//     sim[i][j] = sequential-k fmaf chain over e_i*e_j ; stable top-31
//   Approx sim = ONE fp16 MFMA term (f32 accumulate), fp16-RU scratch.
//   Scratch lives in its OWN 128MB workspace region (ws ~1GiB per the
//   fill kernel), not inside C. emb zeroes ALL of C (256MB coalesced
//   streaming, emb had idle BW); collect loses its 256MB of zero-stores
//   entirely -- it only scans live groups (dead iterations issue ZERO
//   memory ops), runs exact chains, scatters 31 values into the
//   pre-zeroed C. Collect was aggregate-traffic-bound (~1GB); now ~0.75GB
//   with ~1MB of stores.
//   T = 31st of the 128 GROUP maxima (TM2, R22's tighter bound).
//   sim: 128x128 tile, 4 waves, 2-phase double-buffered global_load_lds,
//   single __syncthreads per k-step (race-free), bijective XCD swizzle,
//   LDS 2x16KB -> 4 blocks/CU.
//   cleanup (grid-stride) rewrites flagged rows exactly (row is all-zero
//   until then -- same guarantee as before).

typedef __attribute__((ext_vector_type(8))) short short8;
typedef __attribute__((ext_vector_type(8))) _Float16 half8;
typedef __attribute__((ext_vector_type(4))) float f32x4;

__device__ __forceinline__ float h_elem(const float* __restrict__ f,
                                        const float* __restrict__ W1,
                                        const float* __restrict__ W2, int k) {
  float x = f[k] * W1[k];
  x = fmaxf(x, 0.0f);
  return x * W2[k];
}

// fp16 round-toward-+inf: guarantees decode(f2h_ru(x)) >= x.
// RNE cast, then bump one ulp away-from-(-inf) if it landed below x.
__device__ __forceinline__ unsigned short f2h_ru(float x) {
  _Float16 h = (_Float16)x;  // RNE
  unsigned short b = __builtin_bit_cast(unsigned short, h);
  if ((float)h < x) b = (b & 0x8000u) ? (unsigned short)(b - 1)
                                      : (unsigned short)(b + 1);
  return b;
}
__device__ __forceinline__ float h2f(unsigned short b) {
  return (float)__builtin_bit_cast(_Float16, b);
}
__device__ __forceinline__ unsigned ordmap(float x) {
  unsigned u = __float_as_uint(x);
  return (u & 0x80000000u) ? ~u : (u | 0x80000000u);
}

// async global->LDS, 16B per lane (dest = wave-uniform base + lane*16)
__device__ __forceinline__ void gl16(const void* g, void* l) {
  __builtin_amdgcn_global_load_lds(
      (const __attribute__((address_space(1))) void*)g,
      (__attribute__((address_space(3))) void*)l, 16, 0, 0);
}

// ---------------------------------------------------------------------------
// Kernel A: fused norm (numpy pairwise association, bit-exact) + e = h/n,
// fp16 image (RNE via cast), flag zeroing, AND full zero-fill of this
// block's 4 output rows (128KB coalesced streaming -- emb had idle BW).
// One wave per row.
// ---------------------------------------------------------------------------
__global__ __launch_bounds__(256) void emb_kernel(
    const float* __restrict__ f, const float* __restrict__ W1,
    const float* __restrict__ W2, float* __restrict__ e32,
    _Float16* __restrict__ Ef, int* __restrict__ flags,
    float* __restrict__ C) {
  const int tid = threadIdx.x;
  const int lane = tid & 63;
  const int row = blockIdx.x * 4 + (tid >> 6);
  const float* fr = f + (size_t)row * DD;
  const int b = lane >> 4, L = lane & 15;
  if (lane == 0) flags[row] = 0;

  float s[8];
#pragma unroll
  for (int j = 0; j < 8; ++j) {
    float h = h_elem(fr, W1, W2, b * 128 + 16 * j + L);
    s[j] = h * h;
  }
  float v = ((s[0] + s[1]) + (s[2] + s[3])) + ((s[4] + s[5]) + (s[6] + s[7]));
  float t = v + __shfl_xor(v, 8);
  t = t + __shfl_xor(t, 4);
  t = t + __shfl_xor(t, 2);
  float nb = t + __shfl_xor(t, 1);
  float x = nb + __shfl_xor(nb, 16);
  float norm2 = x + __shfl_xor(x, 32);
  const float n = fmaxf(sqrtf(norm2), 1e-12f);

  float* er = e32 + (size_t)row * DD;
  _Float16* hr = Ef + (size_t)row * DD;
#pragma unroll
  for (int m = 0; m < 8; ++m) {
    int k = m * 64 + lane;
    float e = h_elem(fr, W1, W2, k) / n;
    er[k] = e;
    hr[k] = (_Float16)e;  // RNE
  }

  // zero this block's 4 output rows (4 x 8192 floats = 8192 float4)
  float4* Cz = (float4*)(C + (size_t)(blockIdx.x * 4) * NN);
  const float4 z4 = make_float4(0.f, 0.f, 0.f, 0.f);
#pragma unroll
  for (int i = 0; i < 32; ++i) Cz[i * 256 + tid] = z4;
}

// ---------------------------------------------------------------------------
// Kernel B: single-term fp16 MFMA sim, upper-triangle 128x128 tiles.
// R15-safe 2-phase K-loop (BK=32): STAGE(next buf: 4 gl16) -> 8 frag reads
// + 16 MFMAs (cur buf) -> ONE __syncthreads (race-free drain).
// Linear LDS tiles A|B (8KB each) x 2 buffers (32KB).
// Epilogue: round-up fp16 tile write into the DEDICATED scratch buffer Sh +
// per-row 64-col band maxima TM2 (normal + mirror) + (bx>by) transposed
// mirror tile via LDS strips.
// ---------------------------------------------------------------------------
#define OFS_B 4096    // short offset of B tile within a buffer

#define STAGE(BUF, KK)                       \
  do {                                       \
    char* Ld = L0 + ((BUF) << 14);           \
    gl16(Ef + rA + (KK), Ld);                \
    gl16(Ef + rA + H + (KK), Ld + 4096);     \
    gl16(Ef + rB + (KK), Ld + 8192);         \
    gl16(Ef + rB + H + (KK), Ld + 12288);    \
  } while (0)

__global__ __launch_bounds__(256) void sim_mfma(
    const _Float16* __restrict__ Ef, unsigned short* __restrict__ Sh,
    float* __restrict__ TM2) {
  // bijective XCD swizzle (2080 % 8 == 0): consecutive swz within an XCD
  // share the by-band -> A-panel L2 locality on the XCD's private L2.
  int swz = (blockIdx.x & 7) * 260 + (blockIdx.x >> 3);
  // triangular decode: 2080 -> (bx, by) with bx >= by
  int rem = swz, by = 0;
  while (rem >= 64 - by) { rem -= 64 - by; ++by; }
  const int bx = by + rem;

  __shared__ __align__(16) char smem[34048];  // 2 x 16KB ping-pong; epi alias
  unsigned short* S = (unsigned short*)smem;
  char* Sc = smem;
  float(*Tt)[133] = (float(*)[133])smem;  // epilogue alias ([64][133] = 34048B)
  __shared__ float rmx[128][2];
  __shared__ float cmx[128][2];

  const int t = threadIdx.x;
  const int lane = t & 63, w = t >> 6;
  const int wr = w >> 1, wc = w & 1;
  const int quad = lane >> 4, l16 = lane & 15;
  const int i0 = by * 128, j0 = bx * 128;

  f32x4 acc[4][4];
#pragma unroll
  for (int a = 0; a < 4; ++a)
#pragma unroll
    for (int b = 0; b < 4; ++b) acc[a][b] = (f32x4){0.f, 0.f, 0.f, 0.f};

  // staging: thread t writes LDS bytes [t*16, t*16+16) of each 4KB tensor-half
  // == row (t>>2), chunk (t&3) of a linear [128][32-half] tile.
  const size_t rA = (size_t)(i0 + (t >> 2)) * DD + (t & 3) * 8;
  const size_t rB = (size_t)(j0 + (t >> 2)) * DD + (t & 3) * 8;
  const size_t H = (size_t)64 * DD;
  char* L0 = Sc + (w << 10);  // wave-uniform LDS base

  STAGE(0, 0);
  __syncthreads();

  int cur = 0;
  for (int kk = 0; kk < DD; kk += 32) {
    if (kk + 32 < DD) STAGE(cur ^ 1, kk + 32);  // issue next tile's loads

    const unsigned short* Sb = S + (cur << 13);  // cur*8192 shorts
    half8 ah[4], bh[4];
#pragma unroll
    for (int mt = 0; mt < 4; ++mt)
      ah[mt] = *(const half8*)&Sb[(wr * 64 + mt * 16 + l16) * 32 + quad * 8];
#pragma unroll
    for (int nt = 0; nt < 4; ++nt)
      bh[nt] = *(const half8*)&Sb[OFS_B + (wc * 64 + nt * 16 + l16) * 32 + quad * 8];
#pragma unroll
    for (int mt = 0; mt < 4; ++mt)
#pragma unroll
      for (int nt = 0; nt < 4; ++nt)
        acc[mt][nt] = __builtin_amdgcn_mfma_f32_16x16x32_f16(ah[mt], bh[nt], acc[mt][nt], 0, 0, 0);

    __syncthreads();  // drains next-buf loads + all waves done reading cur
    cur ^= 1;
  }

  // --- normal tile write: round-up fp16 into the scratch buffer ---
#pragma unroll
  for (int mt = 0; mt < 4; ++mt)
#pragma unroll
    for (int r = 0; r < 4; ++r) {
      int row = i0 + wr * 64 + mt * 16 + quad * 4 + r;
      unsigned short* Br = Sh + (size_t)row * NN + j0 + wc * 64;
#pragma unroll
      for (int nt = 0; nt < 4; ++nt) Br[nt * 16 + l16] = f2h_ru(acc[mt][nt][r]);
    }

  // --- per-row 64-col band maxima (rows of this tile); rmx col = wc band ---
#pragma unroll
  for (int mt = 0; mt < 4; ++mt)
#pragma unroll
    for (int r = 0; r < 4; ++r) {
      float m = fmaxf(fmaxf(acc[mt][0][r], acc[mt][1][r]),
                      fmaxf(acc[mt][2][r], acc[mt][3][r]));
      m = fmaxf(m, __shfl_xor(m, 1));
      m = fmaxf(m, __shfl_xor(m, 2));
      m = fmaxf(m, __shfl_xor(m, 4));
      m = fmaxf(m, __shfl_xor(m, 8));
      if (l16 == 0) rmx[wr * 64 + mt * 16 + quad * 4 + r][wc] = m;
    }
  // --- per-col band maxima (rows of the mirrored tile), off-diagonal only ---
  if (bx > by) {
#pragma unroll
    for (int nt = 0; nt < 4; ++nt) {
      float c = -FLT_MAX;
#pragma unroll
      for (int mt = 0; mt < 4; ++mt)
#pragma unroll
        for (int r = 0; r < 4; ++r) c = fmaxf(c, acc[mt][nt][r]);
      c = fmaxf(c, __shfl_xor(c, 16));
      c = fmaxf(c, __shfl_xor(c, 32));
      if (quad == 0) cmx[wc * 64 + nt * 16 + l16][wr] = c;
    }
  }
  __syncthreads();
  // TM2[row][128]: 64-col group maxima. Group index = global_col/64.
  if (t < 128)
    *(float2*)&TM2[(size_t)(i0 + t) * 128 + bx * 2] = *(float2*)&rmx[t][0];
  if (bx > by) {
    // mirror row j0+t: cmx[t][wr] is the max over cols i0+wr*64..+63
    if (t < 128)
      *(float2*)&TM2[(size_t)(j0 + t) * 128 + by * 2] =
          make_float2(cmx[t][0], cmx[t][1]);
    // --- transposed mirror write via LDS strips (Tt aliases S), fp16-RU out ---
    for (int s = 0; s < 2; ++s) {
      __syncthreads();
      if (wc == s) {
#pragma unroll
        for (int mt = 0; mt < 4; ++mt)
#pragma unroll
          for (int nt = 0; nt < 4; ++nt)
#pragma unroll
            for (int r = 0; r < 4; ++r)
              Tt[nt * 16 + l16][wr * 64 + mt * 16 + quad * 4 + r] = acc[mt][nt][r];
      }
      __syncthreads();
#pragma unroll
      for (int q = 0; q < 8; ++q) {
        int fi = q * 256 + t;
        int rr = fi >> 5;
        int cc4 = (fi & 31) * 4;
        ushort4 v;
        v.x = f2h_ru(Tt[rr][cc4]);
        v.y = f2h_ru(Tt[rr][cc4 + 1]);
        v.z = f2h_ru(Tt[rr][cc4 + 2]);
        v.w = f2h_ru(Tt[rr][cc4 + 3]);
        *(ushort4*)(Sh + (size_t)(j0 + s * 64 + rr) * NN + i0 + cc4) = v;
      }
    }
  }
}

// ---------------------------------------------------------------------------
// Kernel C: collect+scatter. One WAVE per row (4 rows/block). Lane l holds
// the float2 TM2 pair for groups (2l, 2l+1). T = 31st largest of the 128
// GROUP maxima via 2-key rank-select (tie-break: group idx asc). Scan over
// the fp16-RU scratch touches ONLY live groups (gmax >= Tc); dead
// iterations issue no memory ops (C was pre-zeroed by emb). Exact fmaf
// chains re-rank into LDS kidx/kval; lanes 0..30 scatter the 31 final
// values into the pre-zeroed C. Overflow -> flag (row stays zero; cleanup
// rewrites it exactly).
// ---------------------------------------------------------------------------
__global__ __launch_bounds__(256) void topk_collect(
    float* __restrict__ C, const float* __restrict__ e32,
    const unsigned short* __restrict__ Sh, const float* __restrict__ TM2,
    int* __restrict__ flags) {
  const int w = threadIdx.x >> 6;
  const int lane = threadIdx.x & 63;
  const int row = blockIdx.x * 4 + w;

  __shared__ float er[4][DD];
  __shared__ int cidx[4][CAPW];
  __shared__ float cval[4][CAPW];
  __shared__ int wcnt[4];
  __shared__ int kidx[4][TOPK];
  __shared__ float kval[4][TOPK];

  {
    const float4* e4 = (const float4*)(e32 + (size_t)row * DD);
    float4* er4 = (float4*)er[w];
    er4[lane] = e4[lane];
    er4[64 + lane] = e4[64 + lane];
  }
  if (lane == 0) wcnt[w] = 0;

  // lane l: group maxima (2l, 2l+1).
  const float2 mv2 = *(const float2*)&TM2[(size_t)row * 128 + 2 * lane];
  const float mva = mv2.x, mvb = mv2.y;

  // T = 31st largest of 128 group maxima: 2-key rank-select.
  // Total order: (value desc, group idx asc); group idx: a=2*lane, b=2*lane+1.
  const unsigned ka = ordmap(mva), kb = ordmap(mvb);
  int ra = (kb > ka) ? 1 : 0;   // own b vs own a (tie: b's idx larger, loses)
  int rb = (ka >= kb) ? 1 : 0;  // own a vs own b (tie: a's idx smaller, wins)
#pragma unroll
  for (int off = 1; off < 64; ++off) {
    int ol = (lane + off) & 63;
    unsigned oa = __shfl(ka, ol);
    unsigned ob = __shfl(kb, ol);
    ra += (oa > ka || (oa == ka && ol < lane)) ? 1 : 0;  // 2ol   vs 2lane
    ra += (ob > ka || (ob == ka && ol < lane)) ? 1 : 0;  // 2ol+1 vs 2lane
    rb += (oa > kb || (oa == kb && ol <= lane)) ? 1 : 0; // 2ol   vs 2lane+1
    rb += (ob > kb || (ob == kb && ol < lane)) ? 1 : 0;  // 2ol+1 vs 2lane+1
  }
  unsigned long long ba = __ballot(ra == TOPK - 1);
  unsigned long long bb = __ballot(rb == TOPK - 1);
  float T;
  if (ba)
    T = __shfl(mva, __ffsll(ba) - 1);
  else
    T = __shfl(mvb, __ffsll(bb) - 1);

  // scan: ONLY live groups touch memory (no zero-stores -- C pre-zeroed).
  // lane's 8 cols in iter it lie in group g = it*8 + (lane>>3);
  // g's max lives at lane g>>1 = it*4+(lane>>4), field g&1 = (lane>>3)&1.
  const float Tc = T - 2.0f * DELTA;
  const int gpar = (lane >> 3) & 1;
  const uint4* Br4 = (const uint4*)(Sh + (size_t)row * NN);
  for (int it = 0; it < NN / 512; ++it) {
    const int srcl = it * 4 + (lane >> 4);
    const float ga = __shfl(mva, srcl);
    const float gb = __shfl(mvb, srcl);
    const float gmx = gpar ? gb : ga;
    if (gmx >= Tc) {
      uint4 v = Br4[it * 64 + lane];
      int j = (it * 64 + lane) * 8;
      unsigned wv[4] = {v.x, v.y, v.z, v.w};
#pragma unroll
      for (int c = 0; c < 4; ++c) {
        float f0 = h2f((unsigned short)(wv[c] & 0xffffu));
        float f1 = h2f((unsigned short)(wv[c] >> 16));
        if (f0 >= Tc) { int p = atomicAdd(&wcnt[w], 1); if (p < CAPW) cidx[w][p] = j + 2 * c; }
        if (f1 >= Tc) { int p = atomicAdd(&wcnt[w], 1); if (p < CAPW) cidx[w][p] = j + 2 * c + 1; }
      }
    }
  }
  const int cnt = wcnt[w];
  const bool ok = (cnt <= CAPW);
  if (!ok && lane == 0) flags[row] = 1;

  // exact sequential-k fmaf chains (bit-identical to the verified chain)
  if (ok) {
    for (int c = lane; c < cnt; c += 64) {
      const float4* ej4 = (const float4*)(e32 + (size_t)cidx[w][c] * DD);
      float a = 0.f;
      for (int k4 = 0; k4 < DD / 4; ++k4) {
        float4 vv = ej4[k4];
        const float* e = &er[w][k4 * 4];
        a = fmaf(e[0], vv.x, a);
        a = fmaf(e[1], vv.y, a);
        a = fmaf(e[2], vv.z, a);
        a = fmaf(e[3], vv.w, a);
      }
      cval[w][c] = a;
    }

    // stable top-31 by (exact desc, idx asc) -> LDS kidx/kval
    for (int c = lane; c < cnt; c += 64) {
      float v = cval[w][c];
      int idx = cidx[w][c];
      int rnk = 0;
      for (int c2 = 0; c2 < cnt; ++c2) {
        float v2 = cval[w][c2];
        if (v2 > v || (v2 == v && cidx[w][c2] < idx)) ++rnk;
      }
      if (rnk < TOPK) {
        kidx[w][rnk] = idx;
        kval[w][rnk] = fmaxf(v, 0.0f);
      }
    }
  }

  __syncthreads();  // publish kidx/kval

  if (ok && lane < TOPK) C[(size_t)row * NN + kidx[w][lane]] = kval[w][lane];
}

// ---------------------------------------------------------------------------
// Kernel D: exact cleanup for flagged rows (statistically never executes).
// 256-block grid-stride; flag check is block-uniform so barriers are safe.
// ---------------------------------------------------------------------------
__global__ __launch_bounds__(256) void cleanup_kernel(
    float* __restrict__ C, const float* __restrict__ e32,
    const int* __restrict__ flags) {
  const int tid = threadIdx.x;
  const int lane = tid & 63, wid = tid >> 6;

  __shared__ float sv[NN];
  __shared__ float er[DD];
  __shared__ unsigned long long wred[4];
  __shared__ int kidx[TOPK];
  __shared__ float kval[TOPK];

  for (int row = blockIdx.x; row < NN; row += 256) {
    if (flags[row] == 0) continue;  // uniform per block

    {
      const float4* e4 = (const float4*)(e32 + (size_t)row * DD);
      if (tid < DD / 4) ((float4*)er)[tid] = e4[tid];
    }
    __syncthreads();

    for (int m = 0; m < NN / 256; ++m) {
      int j = m * 256 + tid;
      const float* ej = e32 + (size_t)j * DD;
      float a = 0.f;
      for (int k = 0; k < DD; k += 4) {
        float4 v = *(const float4*)&ej[k];
        a = fmaf(er[k], v.x, a);
        a = fmaf(er[k + 1], v.y, a);
        a = fmaf(er[k + 2], v.z, a);
        a = fmaf(er[k + 3], v.w, a);
      }
      sv[j] = a;
    }
    __syncthreads();

    for (int it = 0; it < TOPK; ++it) {
      float bv = -FLT_MAX;
      int bi = 0;
      for (int j = tid; j < NN; j += 256) {
        float v = sv[j];
        if (v > bv) { bv = v; bi = j; }
      }
      unsigned long long key =
          ((unsigned long long)ordmap(bv) << 32) | (unsigned)(NN - 1 - bi);
#pragma unroll
      for (int off = 32; off; off >>= 1) {
        unsigned long long o = __shfl_xor(key, off);
        if (o > key) key = o;
      }
      if (lane == 0) wred[wid] = key;
      __syncthreads();
      if (tid == 0) {
        unsigned long long k0 = wred[0];
        if (wred[1] > k0) k0 = wred[1];
        if (wred[2] > k0) k0 = wred[2];
        if (wred[3] > k0) k0 = wred[3];
        int idx = (NN - 1) - (int)(k0 & 0xFFFFFFFFu);
        kidx[it] = idx;
        kval[it] = sv[idx];
        sv[idx] = -FLT_MAX;
      }
      __syncthreads();
    }

    float4 z4 = make_float4(0.f, 0.f, 0.f, 0.f);
    float4* sv4 = (float4*)sv;
    for (int i = tid; i < NN / 4; i += 256) sv4[i] = z4;
    __syncthreads();
    if (tid < TOPK) sv[kidx[tid]] = fmaxf(kval[tid], 0.0f);
    __syncthreads();
    float4* Cw4 = (float4*)(C + (size_t)row * NN);
    for (int i = tid; i < NN / 4; i += 256) Cw4[i] = sv4[i];
    __syncthreads();
  }
}

// ---------------------------------------------------------------------------
extern "C" void kernel_launch(void* const* d_in, const int* in_sizes, int n_in,
                              void* d_out, int out_size, void* d_ws,
                              size_t ws_size, hipStream_t stream) {
  const float* f = (const float*)d_in[0];
  const float* W1 = (const float*)d_in[1];
  const float* W2 = (const float*)d_in[2];
  float* out = (float*)d_out;
  char* ws = (char*)d_ws;
  float* e32 = (float*)ws;                                    // 16 MiB @ 0
  _Float16* Ef = (_Float16*)(ws + (((size_t)16) << 20));      // 8 MiB @ 16M
  float* TM2 = (float*)(ws + (((size_t)24) << 20));           // 4 MiB @ 24M
  int* flags = (int*)(ws + (((size_t)28) << 20));             // 32 KB @ 28M
  unsigned short* Sh =
      (unsigned short*)(ws + (((size_t)29) << 20));           // 128 MiB @ 29M

  emb_kernel<<<NN / 4, 256, 0, stream>>>(f, W1, W2, e32, Ef, flags, out);
  sim_mfma<<<2080, 256, 0, stream>>>(Ef, Sh, TM2);
  topk_collect<<<NN / 4, 256, 0, stream>>>(out, e32, Sh, TM2, flags);
  cleanup_kernel<<<256, 256, 0, stream>>>(out, e32, flags);
}

// Round 18
// 494.744 us; speedup vs baseline: 1.0777x; 1.0777x over previous
//
#include <hip/hip_runtime.h>
#include <float.h>
#include <math.h>

// Problem constants (fixed by the reference: N=8192, D=512, k+1=31).
#define NN 8192
#define DD 512
#define TOPK 31
#define CAPW 192          // per-row candidate cap (typical cnt ~43)
#define DELTA 1.25e-3f    // sound |fp16-1-term approx - exact| bound:
                          // 2*2^-11*||e||^2 (9.8e-4) + f32 accum (~6e-5)

// Strategy (R25 = R22 verbatim, the measured-best 495.1us configuration;
// R24's scratch/output separation regressed -38us and is reverted):
//   Bit-exact value chain (absmax 0.0 since R3):
//     h = relu(f*W1)*W2 ; n = sqrtf(numpy-pairwise sum h*h) ; e = h/n
//     sim[i][j] = sequential-k fmaf chain over e_i*e_j ; stable top-31
//   Approx sim = ONE fp16 MFMA term (f32 accumulate), fp16-RU scratch in
//   the SECOND 16KB of each output f32 row. Sim epilogue exports 64-col
//   band maxima TM2[row][128] (free: already computed as rmx/cmx halves).
//   T = 31st largest of the 128 GROUP maxima (rank-select over 2 keys/lane;
//   sound: T is attained by >=31 distinct cells, so exact_31 >= T - DELTA
//   and every required index has stored >= T - 2*DELTA = Tc).
//   sim: 128x128 tile, 4 waves, 2-phase double-buffered global_load_lds,
//   single __syncthreads per k-step (race-free), bijective XCD swizzle,
//   LDS 2x16KB -> 4 blocks/CU.
//   collect (1 wave/row): 64-col fine-skip scan, zero BOTH row halves
//   during scan (stores ride free in the latency-bound kernel -- R24
//   proved moving them out costs more), exact fmaf chains re-rank to LDS,
//   scatter 31 values after the barrier. cleanup (grid-stride) rewrites
//   flagged rows exactly.

typedef __attribute__((ext_vector_type(8))) short short8;
typedef __attribute__((ext_vector_type(8))) _Float16 half8;
typedef __attribute__((ext_vector_type(4))) float f32x4;

__device__ __forceinline__ float h_elem(const float* __restrict__ f,
                                        const float* __restrict__ W1,
                                        const float* __restrict__ W2, int k) {
  float x = f[k] * W1[k];
  x = fmaxf(x, 0.0f);
  return x * W2[k];
}

// fp16 round-toward-+inf: guarantees decode(f2h_ru(x)) >= x.
// RNE cast, then bump one ulp away-from-(-inf) if it landed below x.
__device__ __forceinline__ unsigned short f2h_ru(float x) {
  _Float16 h = (_Float16)x;  // RNE
  unsigned short b = __builtin_bit_cast(unsigned short, h);
  if ((float)h < x) b = (b & 0x8000u) ? (unsigned short)(b - 1)
                                      : (unsigned short)(b + 1);
  return b;
}
__device__ __forceinline__ float h2f(unsigned short b) {
  return (float)__builtin_bit_cast(_Float16, b);
}
__device__ __forceinline__ unsigned ordmap(float x) {
  unsigned u = __float_as_uint(x);
  return (u & 0x80000000u) ? ~u : (u | 0x80000000u);
}

// async global->LDS, 16B per lane (dest = wave-uniform base + lane*16)
__device__ __forceinline__ void gl16(const void* g, void* l) {
  __builtin_amdgcn_global_load_lds(
      (const __attribute__((address_space(1))) void*)g,
      (__attribute__((address_space(3))) void*)l, 16, 0, 0);
}

// fp16 scratch image of sim row i: second half of output row i's 32KB span.
__device__ __forceinline__ unsigned short* hrow(float* C, int row) {
  return (unsigned short*)C + (size_t)row * (2 * NN) + NN;
}

// ---------------------------------------------------------------------------
// Kernel A: fused norm (numpy pairwise association, bit-exact) + e = h/n,
// fp16 image (RNE via cast), flag zeroing. One wave per row.
// ---------------------------------------------------------------------------
__global__ __launch_bounds__(256) void emb_kernel(
    const float* __restrict__ f, const float* __restrict__ W1,
    const float* __restrict__ W2, float* __restrict__ e32,
    _Float16* __restrict__ Ef, int* __restrict__ flags) {
  const int lane = threadIdx.x & 63;
  const int row = blockIdx.x * 4 + (threadIdx.x >> 6);
  const float* fr = f + (size_t)row * DD;
  const int b = lane >> 4, L = lane & 15;
  if (lane == 0) flags[row] = 0;

  float s[8];
#pragma unroll
  for (int j = 0; j < 8; ++j) {
    float h = h_elem(fr, W1, W2, b * 128 + 16 * j + L);
    s[j] = h * h;
  }
  float v = ((s[0] + s[1]) + (s[2] + s[3])) + ((s[4] + s[5]) + (s[6] + s[7]));
  float t = v + __shfl_xor(v, 8);
  t = t + __shfl_xor(t, 4);
  t = t + __shfl_xor(t, 2);
  float nb = t + __shfl_xor(t, 1);
  float x = nb + __shfl_xor(nb, 16);
  float norm2 = x + __shfl_xor(x, 32);
  const float n = fmaxf(sqrtf(norm2), 1e-12f);

  float* er = e32 + (size_t)row * DD;
  _Float16* hr = Ef + (size_t)row * DD;
#pragma unroll
  for (int m = 0; m < 8; ++m) {
    int k = m * 64 + lane;
    float e = h_elem(fr, W1, W2, k) / n;
    er[k] = e;
    hr[k] = (_Float16)e;  // RNE
  }
}

// ---------------------------------------------------------------------------
// Kernel B: single-term fp16 MFMA sim, upper-triangle 128x128 tiles.
// R15-safe 2-phase K-loop (BK=32): STAGE(next buf: 4 gl16) -> 8 frag reads
// + 16 MFMAs (cur buf) -> ONE __syncthreads (race-free drain).
// Linear LDS tiles A|B (8KB each) x 2 buffers (32KB).
// Epilogue: round-up fp16 tile write into per-row scratch halves + per-row
// 64-col band maxima TM2 (normal + mirror) + (bx>by) transposed mirror tile.
// ---------------------------------------------------------------------------
#define OFS_B 4096    // short offset of B tile within a buffer

#define STAGE(BUF, KK)                       \
  do {                                       \
    char* Ld = L0 + ((BUF) << 14);           \
    gl16(Ef + rA + (KK), Ld);                \
    gl16(Ef + rA + H + (KK), Ld + 4096);     \
    gl16(Ef + rB + (KK), Ld + 8192);         \
    gl16(Ef + rB + H + (KK), Ld + 12288);    \
  } while (0)

__global__ __launch_bounds__(256) void sim_mfma(
    const _Float16* __restrict__ Ef, float* __restrict__ C,
    float* __restrict__ TM2) {
  // bijective XCD swizzle (2080 % 8 == 0): consecutive swz within an XCD
  // share the by-band -> A-panel L2 locality on the XCD's private L2.
  int swz = (blockIdx.x & 7) * 260 + (blockIdx.x >> 3);
  // triangular decode: 2080 -> (bx, by) with bx >= by
  int rem = swz, by = 0;
  while (rem >= 64 - by) { rem -= 64 - by; ++by; }
  const int bx = by + rem;

  __shared__ __align__(16) char smem[34048];  // 2 x 16KB ping-pong; epi alias
  unsigned short* S = (unsigned short*)smem;
  char* Sc = smem;
  float(*Tt)[133] = (float(*)[133])smem;  // epilogue alias ([64][133] = 34048B)
  __shared__ float rmx[128][2];
  __shared__ float cmx[128][2];

  const int t = threadIdx.x;
  const int lane = t & 63, w = t >> 6;
  const int wr = w >> 1, wc = w & 1;
  const int quad = lane >> 4, l16 = lane & 15;
  const int i0 = by * 128, j0 = bx * 128;

  f32x4 acc[4][4];
#pragma unroll
  for (int a = 0; a < 4; ++a)
#pragma unroll
    for (int b = 0; b < 4; ++b) acc[a][b] = (f32x4){0.f, 0.f, 0.f, 0.f};

  // staging: thread t writes LDS bytes [t*16, t*16+16) of each 4KB tensor-half
  // == row (t>>2), chunk (t&3) of a linear [128][32-half] tile.
  const size_t rA = (size_t)(i0 + (t >> 2)) * DD + (t & 3) * 8;
  const size_t rB = (size_t)(j0 + (t >> 2)) * DD + (t & 3) * 8;
  const size_t H = (size_t)64 * DD;
  char* L0 = Sc + (w << 10);  // wave-uniform LDS base

  STAGE(0, 0);
  __syncthreads();

  int cur = 0;
  for (int kk = 0; kk < DD; kk += 32) {
    if (kk + 32 < DD) STAGE(cur ^ 1, kk + 32);  // issue next tile's loads

    const unsigned short* Sb = S + (cur << 13);  // cur*8192 shorts
    half8 ah[4], bh[4];
#pragma unroll
    for (int mt = 0; mt < 4; ++mt)
      ah[mt] = *(const half8*)&Sb[(wr * 64 + mt * 16 + l16) * 32 + quad * 8];
#pragma unroll
    for (int nt = 0; nt < 4; ++nt)
      bh[nt] = *(const half8*)&Sb[OFS_B + (wc * 64 + nt * 16 + l16) * 32 + quad * 8];
#pragma unroll
    for (int mt = 0; mt < 4; ++mt)
#pragma unroll
      for (int nt = 0; nt < 4; ++nt)
        acc[mt][nt] = __builtin_amdgcn_mfma_f32_16x16x32_f16(ah[mt], bh[nt], acc[mt][nt], 0, 0, 0);

    __syncthreads();  // drains next-buf loads + all waves done reading cur
    cur ^= 1;
  }

  // --- normal tile write: round-up fp16 into per-row scratch ---
#pragma unroll
  for (int mt = 0; mt < 4; ++mt)
#pragma unroll
    for (int r = 0; r < 4; ++r) {
      int row = i0 + wr * 64 + mt * 16 + quad * 4 + r;
      unsigned short* Br = hrow(C, row) + j0 + wc * 64;
#pragma unroll
      for (int nt = 0; nt < 4; ++nt) Br[nt * 16 + l16] = f2h_ru(acc[mt][nt][r]);
    }

  // --- per-row 64-col band maxima (rows of this tile); rmx col = wc band ---
#pragma unroll
  for (int mt = 0; mt < 4; ++mt)
#pragma unroll
    for (int r = 0; r < 4; ++r) {
      float m = fmaxf(fmaxf(acc[mt][0][r], acc[mt][1][r]),
                      fmaxf(acc[mt][2][r], acc[mt][3][r]));
      m = fmaxf(m, __shfl_xor(m, 1));
      m = fmaxf(m, __shfl_xor(m, 2));
      m = fmaxf(m, __shfl_xor(m, 4));
      m = fmaxf(m, __shfl_xor(m, 8));
      if (l16 == 0) rmx[wr * 64 + mt * 16 + quad * 4 + r][wc] = m;
    }
  // --- per-col band maxima (rows of the mirrored tile), off-diagonal only ---
  if (bx > by) {
#pragma unroll
    for (int nt = 0; nt < 4; ++nt) {
      float c = -FLT_MAX;
#pragma unroll
      for (int mt = 0; mt < 4; ++mt)
#pragma unroll
        for (int r = 0; r < 4; ++r) c = fmaxf(c, acc[mt][nt][r]);
      c = fmaxf(c, __shfl_xor(c, 16));
      c = fmaxf(c, __shfl_xor(c, 32));
      if (quad == 0) cmx[wc * 64 + nt * 16 + l16][wr] = c;
    }
  }
  __syncthreads();
  // TM2[row][128]: 64-col group maxima. Group index = global_col/64.
  if (t < 128)
    *(float2*)&TM2[(size_t)(i0 + t) * 128 + bx * 2] = *(float2*)&rmx[t][0];
  if (bx > by) {
    // mirror row j0+t: cmx[t][wr] is the max over cols i0+wr*64..+63
    if (t < 128)
      *(float2*)&TM2[(size_t)(j0 + t) * 128 + by * 2] =
          make_float2(cmx[t][0], cmx[t][1]);
    // --- transposed mirror write via LDS strips (Tt aliases S), fp16-RU out ---
    for (int s = 0; s < 2; ++s) {
      __syncthreads();
      if (wc == s) {
#pragma unroll
        for (int mt = 0; mt < 4; ++mt)
#pragma unroll
          for (int nt = 0; nt < 4; ++nt)
#pragma unroll
            for (int r = 0; r < 4; ++r)
              Tt[nt * 16 + l16][wr * 64 + mt * 16 + quad * 4 + r] = acc[mt][nt][r];
      }
      __syncthreads();
#pragma unroll
      for (int q = 0; q < 8; ++q) {
        int fi = q * 256 + t;
        int rr = fi >> 5;
        int cc4 = (fi & 31) * 4;
        ushort4 v;
        v.x = f2h_ru(Tt[rr][cc4]);
        v.y = f2h_ru(Tt[rr][cc4 + 1]);
        v.z = f2h_ru(Tt[rr][cc4 + 2]);
        v.w = f2h_ru(Tt[rr][cc4 + 3]);
        *(ushort4*)(hrow(C, j0 + s * 64 + rr) + i0 + cc4) = v;
      }
    }
  }
}

// ---------------------------------------------------------------------------
// Kernel C: collect+write. One WAVE per row (4 rows/block). Lane l holds the
// float2 TM2 pair for groups (2l, 2l+1). T = 31st largest of the 128 GROUP
// maxima via 2-key rank-select (tie-break: group idx asc). Single pass over
// the fp16-RU row scratch: SKIP loads at 64-col granularity (gmax < Tc ->
// no candidate; sound), collect cands >= Tc, zero BOTH halves of the output
// row. Exact fmaf chains re-rank into LDS kidx/kval; __syncthreads (vmcnt
// drain: zeros committed); lanes 0..30 scatter the 31 final values.
// Overflow -> flag, predicated skip (cleanup rewrites).
// ---------------------------------------------------------------------------
__global__ __launch_bounds__(256) void topk_collect(
    float* __restrict__ C, const float* __restrict__ e32,
    const float* __restrict__ TM2, int* __restrict__ flags) {
  const int w = threadIdx.x >> 6;
  const int lane = threadIdx.x & 63;
  const int row = blockIdx.x * 4 + w;

  __shared__ float er[4][DD];
  __shared__ int cidx[4][CAPW];
  __shared__ float cval[4][CAPW];
  __shared__ int wcnt[4];
  __shared__ int kidx[4][TOPK];
  __shared__ float kval[4][TOPK];

  {
    const float4* e4 = (const float4*)(e32 + (size_t)row * DD);
    float4* er4 = (float4*)er[w];
    er4[lane] = e4[lane];
    er4[64 + lane] = e4[64 + lane];
  }
  if (lane == 0) wcnt[w] = 0;

  // lane l: group maxima (2l, 2l+1).
  const float2 mv2 = *(const float2*)&TM2[(size_t)row * 128 + 2 * lane];
  const float mva = mv2.x, mvb = mv2.y;

  // T = 31st largest of 128 group maxima: 2-key rank-select.
  // Total order: (value desc, group idx asc); group idx: a=2*lane, b=2*lane+1.
  const unsigned ka = ordmap(mva), kb = ordmap(mvb);
  int ra = (kb > ka) ? 1 : 0;   // own b vs own a (tie: b's idx larger, loses)
  int rb = (ka >= kb) ? 1 : 0;  // own a vs own b (tie: a's idx smaller, wins)
#pragma unroll
  for (int off = 1; off < 64; ++off) {
    int ol = (lane + off) & 63;
    unsigned oa = __shfl(ka, ol);
    unsigned ob = __shfl(kb, ol);
    ra += (oa > ka || (oa == ka && ol < lane)) ? 1 : 0;  // 2ol   vs 2lane
    ra += (ob > ka || (ob == ka && ol < lane)) ? 1 : 0;  // 2ol+1 vs 2lane
    rb += (oa > kb || (oa == kb && ol <= lane)) ? 1 : 0; // 2ol   vs 2lane+1
    rb += (ob > kb || (ob == kb && ol < lane)) ? 1 : 0;  // 2ol+1 vs 2lane+1
  }
  unsigned long long ba = __ballot(ra == TOPK - 1);
  unsigned long long bb = __ballot(rb == TOPK - 1);
  float T;
  if (ba)
    T = __shfl(mva, __ffsll(ba) - 1);
  else
    T = __shfl(mvb, __ffsll(bb) - 1);

  // single row pass: 64-col fine-skip scan + candidates + zero both halves.
  // lane's 8 cols in iter it lie in group g = it*8 + (lane>>3);
  // g's max lives at lane g>>1 = it*4+(lane>>4), field g&1 = (lane>>3)&1.
  const float Tc = T - 2.0f * DELTA;
  const int gpar = (lane >> 3) & 1;
  unsigned short* Brow = hrow(C, row);
  const uint4* Br4 = (const uint4*)Brow;
  uint4* Bw4 = (uint4*)Brow;                      // scratch half (16KB)
  float4* Zw4 = (float4*)(C + (size_t)row * NN);  // first 16KB = 1024 float4
  const float4 z4 = make_float4(0.f, 0.f, 0.f, 0.f);
  const uint4 zu4 = {0u, 0u, 0u, 0u};
  for (int it = 0; it < NN / 512; ++it) {
    const int srcl = it * 4 + (lane >> 4);
    const float ga = __shfl(mva, srcl);
    const float gb = __shfl(mvb, srcl);
    const float gmx = gpar ? gb : ga;
    const bool live = (gmx >= Tc);
    uint4 v = zu4;
    if (live) v = Br4[it * 64 + lane];
    Zw4[it * 64 + lane] = z4;
    Bw4[it * 64 + lane] = zu4;
    if (live) {
      int j = (it * 64 + lane) * 8;
      unsigned wv[4] = {v.x, v.y, v.z, v.w};
#pragma unroll
      for (int c = 0; c < 4; ++c) {
        float f0 = h2f((unsigned short)(wv[c] & 0xffffu));
        float f1 = h2f((unsigned short)(wv[c] >> 16));
        if (f0 >= Tc) { int p = atomicAdd(&wcnt[w], 1); if (p < CAPW) cidx[w][p] = j + 2 * c; }
        if (f1 >= Tc) { int p = atomicAdd(&wcnt[w], 1); if (p < CAPW) cidx[w][p] = j + 2 * c + 1; }
      }
    }
  }
  const int cnt = wcnt[w];
  const bool ok = (cnt <= CAPW);
  if (!ok && lane == 0) flags[row] = 1;

  // exact sequential-k fmaf chains (bit-identical to the verified chain)
  if (ok) {
    for (int c = lane; c < cnt; c += 64) {
      const float4* ej4 = (const float4*)(e32 + (size_t)cidx[w][c] * DD);
      float a = 0.f;
      for (int k4 = 0; k4 < DD / 4; ++k4) {
        float4 vv = ej4[k4];
        const float* e = &er[w][k4 * 4];
        a = fmaf(e[0], vv.x, a);
        a = fmaf(e[1], vv.y, a);
        a = fmaf(e[2], vv.z, a);
        a = fmaf(e[3], vv.w, a);
      }
      cval[w][c] = a;
    }

    // stable top-31 by (exact desc, idx asc) -> LDS kidx/kval
    for (int c = lane; c < cnt; c += 64) {
      float v = cval[w][c];
      int idx = cidx[w][c];
      int rnk = 0;
      for (int c2 = 0; c2 < cnt; ++c2) {
        float v2 = cval[w][c2];
        if (v2 > v || (v2 == v && cidx[w][c2] < idx)) ++rnk;
      }
      if (rnk < TOPK) {
        kidx[w][rnk] = idx;
        kval[w][rnk] = fmaxf(v, 0.0f);
      }
    }
  }

  // barrier drains all zero-stores (vmcnt 0) and publishes kidx/kval;
  // same-address ordering through L2 then serializes zero -> value.
  __syncthreads();

  if (ok && lane < TOPK) C[(size_t)row * NN + kidx[w][lane]] = kval[w][lane];
}

// ---------------------------------------------------------------------------
// Kernel D: exact cleanup for flagged rows (statistically never executes).
// 256-block grid-stride; flag check is block-uniform so barriers are safe.
// ---------------------------------------------------------------------------
__global__ __launch_bounds__(256) void cleanup_kernel(
    float* __restrict__ C, const float* __restrict__ e32,
    const int* __restrict__ flags) {
  const int tid = threadIdx.x;
  const int lane = tid & 63, wid = tid >> 6;

  __shared__ float sv[NN];
  __shared__ float er[DD];
  __shared__ unsigned long long wred[4];
  __shared__ int kidx[TOPK];
  __shared__ float kval[TOPK];

  for (int row = blockIdx.x; row < NN; row += 256) {
    if (flags[row] == 0) continue;  // uniform per block

    {
      const float4* e4 = (const float4*)(e32 + (size_t)row * DD);
      if (tid < DD / 4) ((float4*)er)[tid] = e4[tid];
    }
    __syncthreads();

    for (int m = 0; m < NN / 256; ++m) {
      int j = m * 256 + tid;
      const float* ej = e32 + (size_t)j * DD;
      float a = 0.f;
      for (int k = 0; k < DD; k += 4) {
        float4 v = *(const float4*)&ej[k];
        a = fmaf(er[k], v.x, a);
        a = fmaf(er[k + 1], v.y, a);
        a = fmaf(er[k + 2], v.z, a);
        a = fmaf(er[k + 3], v.w, a);
      }
      sv[j] = a;
    }
    __syncthreads();

    for (int it = 0; it < TOPK; ++it) {
      float bv = -FLT_MAX;
      int bi = 0;
      for (int j = tid; j < NN; j += 256) {
        float v = sv[j];
        if (v > bv) { bv = v; bi = j; }
      }
      unsigned long long key =
          ((unsigned long long)ordmap(bv) << 32) | (unsigned)(NN - 1 - bi);
#pragma unroll
      for (int off = 32; off; off >>= 1) {
        unsigned long long o = __shfl_xor(key, off);
        if (o > key) key = o;
      }
      if (lane == 0) wred[wid] = key;
      __syncthreads();
      if (tid == 0) {
        unsigned long long k0 = wred[0];
        if (wred[1] > k0) k0 = wred[1];
        if (wred[2] > k0) k0 = wred[2];
        if (wred[3] > k0) k0 = wred[3];
        int idx = (NN - 1) - (int)(k0 & 0xFFFFFFFFu);
        kidx[it] = idx;
        kval[it] = sv[idx];
        sv[idx] = -FLT_MAX;
      }
      __syncthreads();
    }

    float4 z4 = make_float4(0.f, 0.f, 0.f, 0.f);
    float4* sv4 = (float4*)sv;
    for (int i = tid; i < NN / 4; i += 256) sv4[i] = z4;
    __syncthreads();
    if (tid < TOPK) sv[kidx[tid]] = fmaxf(kval[tid], 0.0f);
    __syncthreads();
    float4* Cw4 = (float4*)(C + (size_t)row * NN);
    for (int i = tid; i < NN / 4; i += 256) Cw4[i] = sv4[i];
    __syncthreads();
  }
}

// ---------------------------------------------------------------------------
extern "C" void kernel_launch(void* const* d_in, const int* in_sizes, int n_in,
                              void* d_out, int out_size, void* d_ws,
                              size_t ws_size, hipStream_t stream) {
  const float* f = (const float*)d_in[0];
  const float* W1 = (const float*)d_in[1];
  const float* W2 = (const float*)d_in[2];
  float* out = (float*)d_out;
  char* ws = (char*)d_ws;
  float* e32 = (float*)ws;                                     // 16 MiB
  _Float16* Ef = (_Float16*)(ws + (size_t)NN * DD * 4);        // 8 MiB
  float* TM2 = (float*)(ws + (size_t)NN * DD * 6);             // 4 MiB (NN*128)
  int* flags = (int*)(ws + (size_t)NN * DD * 6 + (size_t)NN * 128 * 4);  // 32 KB

  emb_kernel<<<NN / 4, 256, 0, stream>>>(f, W1, W2, e32, Ef, flags);
  sim_mfma<<<2080, 256, 0, stream>>>(Ef, out, TM2);
  topk_collect<<<NN / 4, 256, 0, stream>>>(out, e32, TM2, flags);
  cleanup_kernel<<<256, 256, 0, stream>>>(out, e32, flags);
}